// Round 5
// baseline (91.381 us; speedup 1.0000x reference)
//
#include <hip/hip_runtime.h>
#include <math.h>

#define B_ 8
#define BIGF 3.4e38f

// ws layout (16-B aligned base):
//   packT  : B_*N float4  {-2x,-2y,-2z,|t|^2}
//   packS  : B_*M float4  { x,  y,  z, |s|^2}
//   colmin : B_*M uint    (per-source min d^2, uint-ordered floats)
//   partials_c : (N/64)*B_ floats (per-block sum of sqrt row-mins)
//   partials_a : B_*M/256 floats  (per-block sum of sqrt col-mins)

__global__ __launch_bounds__(256) void pack_kernel(
    const float* __restrict__ tar, const float* __restrict__ src,
    float4* __restrict__ packT, float4* __restrict__ packS,
    unsigned int* __restrict__ colmin, int N, int M)
{
    const int i = blockIdx.x * 256 + threadIdx.x;
    const int nT = B_ * N, nS = B_ * M;
    if (i < nT) {
        float x = tar[3 * i], y = tar[3 * i + 1], z = tar[3 * i + 2];
        packT[i] = make_float4(-2.f * x, -2.f * y, -2.f * z,
                               fmaf(x, x, fmaf(y, y, z * z)));
    } else if (i < nT + nS) {
        int j = i - nT;
        float x = src[3 * j], y = src[3 * j + 1], z = src[3 * j + 2];
        packS[j] = make_float4(x, y, z, fmaf(x, x, fmaf(y, y, z * z)));
    }
    if (i < nS) colmin[i] = 0x7F800000u;  // +inf
}

// One pass over all (n,m) pairs, feeding BOTH direction mins.
// grid = (N/64 strips, B_ batches), 256 threads.
// lane = tyl*16+tx; lane owns rows strip*64 + tyl*16 + r (r<16) and, per
// m-chunk, cols ch*64 + cr*16 + tx (cr<4). Waves stride disjoint m-chunks.
// d^2 = (|t|^2) + (|s|^2 - 2 t.s) = fma3(a, p, p.w) + a.w.
// 2x2 sub-tiles: both row- and col-folds are v_min3 -> 5 VALU/pair.
__global__ __launch_bounds__(256) void fused_kernel(
    const float4* __restrict__ packT, const float4* __restrict__ packS,
    unsigned int* __restrict__ colmin, float* __restrict__ partials_c,
    int N, int M)
{
    const int b = blockIdx.y;
    const int strip = blockIdx.x;
    const int t = threadIdx.x;
    const int wave = t >> 6, lane = t & 63;
    const int tx = lane & 15, tyl = lane >> 4;

    const float4* __restrict__ pT = packT + (size_t)b * N + strip * 64;
    const float4* __restrict__ pS = packS + (size_t)b * M;
    unsigned int* __restrict__ cm_out = colmin + (size_t)b * M;

    float4 a[16];
#pragma unroll
    for (int r = 0; r < 16; ++r) a[r] = pT[tyl * 16 + r];
    float rmin[16];
#pragma unroll
    for (int r = 0; r < 16; ++r) rmin[r] = BIGF;

    const int nch = M >> 6;      // 64-col chunks
    int ch = wave;
    float4 p[4], pn[4];
    if (ch < nch) {
#pragma unroll
        for (int cr = 0; cr < 4; ++cr) p[cr] = pS[ch * 64 + cr * 16 + tx];
    }
    for (; ch < nch; ch += 4) {
        const int chn = ch + 4;
        if (chn < nch) {
#pragma unroll
            for (int cr = 0; cr < 4; ++cr) pn[cr] = pS[chn * 64 + cr * 16 + tx];
        }
#pragma unroll
        for (int cp = 0; cp < 4; cp += 2) {
            const float4 P0 = p[cp], P1 = p[cp + 1];
            float c0 = BIGF, c1 = BIGF;
#pragma unroll
            for (int r = 0; r < 16; r += 2) {
                float d00 = fmaf(a[r].x, P0.x, fmaf(a[r].y, P0.y,
                            fmaf(a[r].z, P0.z, P0.w))) + a[r].w;
                float d01 = fmaf(a[r].x, P1.x, fmaf(a[r].y, P1.y,
                            fmaf(a[r].z, P1.z, P1.w))) + a[r].w;
                float d10 = fmaf(a[r+1].x, P0.x, fmaf(a[r+1].y, P0.y,
                            fmaf(a[r+1].z, P0.z, P0.w))) + a[r+1].w;
                float d11 = fmaf(a[r+1].x, P1.x, fmaf(a[r+1].y, P1.y,
                            fmaf(a[r+1].z, P1.z, P1.w))) + a[r+1].w;
                rmin[r]   = fminf(rmin[r],   fminf(d00, d01));   // v_min3
                rmin[r+1] = fminf(rmin[r+1], fminf(d10, d11));
                c0 = fminf(c0, fminf(d00, d10));
                c1 = fminf(c1, fminf(d01, d11));
            }
            // fold col-mins across the 4 ty lanes (rows covered in-wave)
            c0 = fminf(c0, __shfl_xor(c0, 16));
            c0 = fminf(c0, __shfl_xor(c0, 32));
            c1 = fminf(c1, __shfl_xor(c1, 16));
            c1 = fminf(c1, __shfl_xor(c1, 32));
            if (tyl == 0) {   // 16 lanes, 64B coalesced, 64 contenders/addr
                atomicMin(&cm_out[ch * 64 + cp * 16 + tx],
                          __float_as_uint(fmaxf(c0, 0.f)));
                atomicMin(&cm_out[ch * 64 + (cp + 1) * 16 + tx],
                          __float_as_uint(fmaxf(c1, 0.f)));
            }
        }
#pragma unroll
        for (int cr = 0; cr < 4; ++cr) p[cr] = pn[cr];
    }

    // Row-mins: fold across tx (16 lanes share each row), then across waves.
#pragma unroll
    for (int r = 0; r < 16; ++r) {
        float v = rmin[r];
        v = fminf(v, __shfl_xor(v, 1));
        v = fminf(v, __shfl_xor(v, 2));
        v = fminf(v, __shfl_xor(v, 4));
        v = fminf(v, __shfl_xor(v, 8));
        rmin[r] = v;
    }
    __shared__ float wr[4][64];
    if (tx == 0) {
#pragma unroll
        for (int r = 0; r < 16; ++r) wr[wave][tyl * 16 + r] = rmin[r];
    }
    __syncthreads();
    if (wave == 0) {
        float v = fminf(fminf(wr[0][lane], wr[1][lane]),
                        fminf(wr[2][lane], wr[3][lane]));
        float s = sqrtf(fmaxf(v, 0.f));
#pragma unroll
        for (int off = 32; off > 0; off >>= 1) s += __shfl_down(s, off);
        if (lane == 0) partials_c[b * gridDim.x + strip] = s;
    }
}

// Sum sqrt(col-mins): one value per thread, block partial via plain store.
__global__ __launch_bounds__(256) void colsum_kernel(
    const unsigned int* __restrict__ colmin, float* __restrict__ partials_a,
    int total)
{
    const int gid = blockIdx.x * 256 + threadIdx.x;
    float s = 0.f;
    if (gid < total) s = sqrtf(fmaxf(__uint_as_float(colmin[gid]), 0.f));
#pragma unroll
    for (int off = 32; off > 0; off >>= 1) s += __shfl_down(s, off);
    __shared__ float rs[4];
    if ((threadIdx.x & 63) == 0) rs[threadIdx.x >> 6] = s;
    __syncthreads();
    if (threadIdx.x == 0)
        partials_a[blockIdx.x] = rs[0] + rs[1] + rs[2] + rs[3];
}

__global__ __launch_bounds__(256) void finalize_kernel(
    const float* __restrict__ partials_c, const float* __restrict__ partials_a,
    float* __restrict__ outp, int nc, int na, int N, int M)
{
    const int t = threadIdx.x;
    float sc = 0.f, sa = 0.f;
    for (int i = t; i < nc; i += 256) sc += partials_c[i];
    for (int i = t; i < na; i += 256) sa += partials_a[i];
#pragma unroll
    for (int off = 32; off > 0; off >>= 1) {
        sc += __shfl_down(sc, off);
        sa += __shfl_down(sa, off);
    }
    __shared__ float rc[4], ra[4];
    const int wid = t >> 6, lid = t & 63;
    if (lid == 0) { rc[wid] = sc; ra[wid] = sa; }
    __syncthreads();
    if (t == 0) {
        float complete = (rc[0] + rc[1] + rc[2] + rc[3]) / (float)(B_ * N);
        float accuracy = (ra[0] + ra[1] + ra[2] + ra[3]) / (float)(B_ * M);
        outp[0] = accuracy;
        outp[1] = complete;
        outp[2] = 0.5f * (accuracy + complete);
    }
}

extern "C" void kernel_launch(void* const* d_in, const int* in_sizes, int n_in,
                              void* d_out, int out_size, void* d_ws, size_t ws_size,
                              hipStream_t stream) {
    const float* tar = (const float*)d_in[0];
    const float* src = (const float*)d_in[1];
    const int N = in_sizes[0] / (B_ * 3);
    const int M = in_sizes[1] / (B_ * 3);

    float4* packT = (float4*)d_ws;
    float4* packS = packT + (size_t)B_ * N;
    unsigned int* colmin = (unsigned int*)(packS + (size_t)B_ * M);
    float* partials_c = (float*)(colmin + (size_t)B_ * M);
    const int nstrips = N / 64;
    const int nc = nstrips * B_;
    const int na = (B_ * M + 255) / 256;
    float* partials_a = partials_c + nc;

    pack_kernel<<<dim3((B_ * (N + M) + 255) / 256), dim3(256), 0, stream>>>(
        tar, src, packT, packS, colmin, N, M);

    fused_kernel<<<dim3(nstrips, B_), dim3(256), 0, stream>>>(
        packT, packS, colmin, partials_c, N, M);

    colsum_kernel<<<dim3(na), dim3(256), 0, stream>>>(colmin, partials_a, B_ * M);

    finalize_kernel<<<dim3(1), dim3(256), 0, stream>>>(
        partials_c, partials_a, (float*)d_out, nc, na, N, M);
}